// Round 4
// baseline (127.444 us; speedup 1.0000x reference)
//
#include <hip/hip_runtime.h>
#include <math.h>

// Problem constants
#define N_IMG 16
#define C_CH 3
#define H_DIM 512
#define W_DIM 512
#define HW (H_DIM * W_DIM)              // 262144
#define KS 7
#define PAD 3

// Tiling: 64 wide x 32 tall output tile, 3-halo each side.
#define TSX 64
#define TSY 32
#define TILE_H (TSY + 2 * PAD)          // 38
#define TSTRIDE 72                      // LDS row stride (floats); interior at [4..67], halos [1..3],[68..70]
#define TPB 256
#define TILES_X (W_DIM / TSX)           // 8
#define TILES_Y (H_DIM / TSY)           // 16
#define TILES_PER_IMG (TILES_X * TILES_Y)   // 128
#define NBLOCKS (N_IMG * TILES_PER_IMG)     // 2048

__device__ __forceinline__ int reflect_i(int g, int n) {
    // jnp 'reflect' (no edge duplication)
    return (g < 0) ? -g : ((g >= n) ? (2 * n - 2 - g) : g);
}

// ---------------------------------------------------------------------------
// Fused kernel: residual tile (reflect halo) from pred/target, float4 interior
// loads + b128 LDS staging; 7x7 local unbiased variance via ring-buffer row
// sums (8 px/thread); per-block partials {sum r, sum r^2, sum var*r} -> ws.
// ---------------------------------------------------------------------------
__global__ __launch_bounds__(TPB) void k_fused(const float* __restrict__ pred,
                                               const float* __restrict__ targ,
                                               float* __restrict__ pr,
                                               float* __restrict__ pr2,
                                               float* __restrict__ pc) {
    __shared__ __align__(16) float tile[TILE_H * TSTRIDE];

    const int bid = blockIdx.x;
    const int n   = bid >> 7;              // 128 tiles per image
    const int t   = bid & 127;
    const int by  = t >> 3;                // 0..15
    const int bx  = t & 7;                 // 0..7
    const int tid = threadIdx.x;

    const int y0 = by * TSY - PAD;

    const float*  pb = pred + (size_t)n * C_CH * HW;
    const float*  qb = targ + (size_t)n * C_CH * HW;
    const float4* P  = (const float4*)pb;
    const float4* Q  = (const float4*)qb;
    const int PL4 = HW / 4;                // plane stride in float4

    // --- interior: 38 rows x 16 float4 (aligned, no horizontal reflect) ---
    // 608 slots = 2*256 + 96
#pragma unroll
    for (int it = 0; it < 3; ++it) {
        const int s = tid + it * TPB;
        if (it < 2 || tid < 96) {
            const int row = s >> 4;
            const int c4  = s & 15;
            const int gy  = reflect_i(y0 + row, H_DIM);
            const int off = gy * (W_DIM / 4) + bx * 16 + c4;
            const float4 p0 = P[off], p1 = P[off + PL4], p2 = P[off + 2 * PL4];
            const float4 q0 = Q[off], q1 = Q[off + PL4], q2 = Q[off + 2 * PL4];
            float4 r;
            r.x = fabsf(q0.x - p0.x) + fabsf(q1.x - p1.x) + fabsf(q2.x - p2.x);
            r.y = fabsf(q0.y - p0.y) + fabsf(q1.y - p1.y) + fabsf(q2.y - p2.y);
            r.z = fabsf(q0.z - p0.z) + fabsf(q1.z - p1.z) + fabsf(q2.z - p2.z);
            r.w = fabsf(q0.w - p0.w) + fabsf(q1.w - p1.w) + fabsf(q2.w - p2.w);
            *(float4*)&tile[row * TSTRIDE + 4 + c4 * 4] = r;   // 16B-aligned
        }
    }
    // --- halo: 38 rows x (3 left + 3 right) scalars ---
    if (tid < TILE_H * 6) {
        const int row = tid / 6;
        const int k   = tid - row * 6;
        const int lx  = (k < 3) ? (1 + k) : (65 + k);          // 1..3 or 68..70
        const int gx  = reflect_i(bx * TSX + lx - 4, W_DIM);
        const int gy  = reflect_i(y0 + row, H_DIM);
        const int off = gy * W_DIM + gx;
        tile[row * TSTRIDE + lx] = fabsf(qb[off] - pb[off])
                                 + fabsf(qb[off + HW] - pb[off + HW])
                                 + fabsf(qb[off + 2 * HW] - pb[off + 2 * HW]);
    }
    __syncthreads();

    // --- 8 vertically-adjacent output pixels per thread (ring of row sums) ---
    const int tx = tid & 63;               // output column 0..63
    const int r0 = (tid >> 6) << 3;        // output rows r0..r0+7

    float rS[KS], rSS[KS];
    float S = 0.f, SS = 0.f;
#pragma unroll
    for (int d = 0; d < KS; ++d) {
        const float* rw = &tile[(r0 + d) * TSTRIDE + 1 + tx];
        float s = 0.f, ss = 0.f;
#pragma unroll
        for (int j = 0; j < KS; ++j) { const float v = rw[j]; s += v; ss += v * v; }
        rS[d] = s; rSS[d] = ss; S += s; SS += ss;
    }

    float acc_r = 0.f, acc_r2 = 0.f, acc_c = 0.f;
#pragma unroll
    for (int k = 0; k < 8; ++k) {
        if (k > 0) {
            const float* rw = &tile[(r0 + 6 + k) * TSTRIDE + 1 + tx];
            float s = 0.f, ss = 0.f;
#pragma unroll
            for (int j = 0; j < KS; ++j) { const float v = rw[j]; s += v; ss += v * v; }
            S  += s  - rS[k - 1];          // slot k-1 never reused (only 7 slides)
            SS += ss - rSS[k - 1];
        }
        const float pix_var = (SS - S * S * (1.0f / 49.0f)) * (1.0f / 48.0f);
        const float center  = tile[(r0 + k + 3) * TSTRIDE + 4 + tx];
        acc_r  += center;
        acc_r2 += center * center;
        acc_c  += pix_var * center;
    }

    // --- block reduce 3 floats ---
#pragma unroll
    for (int off = 32; off > 0; off >>= 1) {
        acc_r  += __shfl_down(acc_r,  off);
        acc_r2 += __shfl_down(acc_r2, off);
        acc_c  += __shfl_down(acc_c,  off);
    }
    __shared__ float sh_r[4], sh_r2[4], sh_c[4];
    const int lane = tid & 63;
    const int wave = tid >> 6;
    if (lane == 0) { sh_r[wave] = acc_r; sh_r2[wave] = acc_r2; sh_c[wave] = acc_c; }
    __syncthreads();
    if (tid == 0) {
        pr [bid] = sh_r [0] + sh_r [1] + sh_r [2] + sh_r [3];
        pr2[bid] = sh_r2[0] + sh_r2[1] + sh_r2[2] + sh_r2[3];
        pc [bid] = sh_c [0] + sh_c [1] + sh_c [2] + sh_c [3];
    }
}

// ---------------------------------------------------------------------------
// Finalize: wave w reduces image w's 128 partials in double; lane 0 applies
// pw_n = pvar^0.2; thread 0 sums the 16 images and writes the scalar.
// ---------------------------------------------------------------------------
__global__ void k_final(const float* __restrict__ pr,
                        const float* __restrict__ pr2,
                        const float* __restrict__ pc,
                        float* __restrict__ out) {
    __shared__ double sh[N_IMG];
    const int tid  = threadIdx.x;       // 1024 threads = 16 waves
    const int w    = tid >> 6;          // image index
    const int lane = tid & 63;

    double R = 0.0, R2 = 0.0, Cs = 0.0;
    for (int i = lane; i < TILES_PER_IMG; i += 64) {
        const int idx = w * TILES_PER_IMG + i;
        R  += (double)pr[idx];
        R2 += (double)pr2[idx];
        Cs += (double)pc[idx];
    }
#pragma unroll
    for (int off = 32; off > 0; off >>= 1) {
        R  += __shfl_down(R,  off);
        R2 += __shfl_down(R2, off);
        Cs += __shfl_down(Cs, off);
    }
    if (lane == 0) {
        const double pvar = (R2 - R * R / (double)HW) / (double)(HW - 1);
        sh[w] = pow(pvar, 0.2) * Cs;
    }
    __syncthreads();
    if (tid == 0) {
        double s = 0.0;
        for (int i = 0; i < N_IMG; ++i) s += sh[i];
        out[0] = (float)(s / ((double)N_IMG * C_CH * HW));
    }
}

extern "C" void kernel_launch(void* const* d_in, const int* in_sizes, int n_in,
                              void* d_out, int out_size, void* d_ws, size_t ws_size,
                              hipStream_t stream) {
    const float* pred = (const float*)d_in[0];
    const float* targ = (const float*)d_in[1];

    float* pr  = (float*)d_ws;
    float* pr2 = pr  + NBLOCKS;
    float* pc  = pr2 + NBLOCKS;
    float* out = (float*)d_out;

    k_fused<<<NBLOCKS, TPB, 0, stream>>>(pred, targ, pr, pr2, pc);
    k_final<<<1, 1024, 0, stream>>>(pr, pr2, pc, out);
}